// Round 5
// baseline (284.841 us; speedup 1.0000x reference)
//
#include <hip/hip_runtime.h>
#include <hip/hip_fp16.h>
#include <math.h>

#define HW 240
#define PITCH 241           // float2 pitch; +1 breaks power-of-2 strides
#define IMG_PIX (HW*HW)     // 57600
#define NB 15               // kw blocks per image
#define TILE_ELEMS (240*16) // elements per blocked chunk

__device__ __forceinline__ float2 cmul(float2 a, float2 b){
    return make_float2(a.x*b.x - a.y*b.y, a.x*b.y + a.y*b.x);
}
__device__ __forceinline__ float2 cadd(float2 a, float2 b){
    return make_float2(a.x+b.x, a.y+b.y);
}
__device__ __forceinline__ float2 csub(float2 a, float2 b){
    return make_float2(a.x-b.x, a.y-b.y);
}
__device__ __forceinline__ __half2 f2h(float2 a){ return __floats2half2_rn(a.x, a.y); }
__device__ __forceinline__ float2 h2f(__half2 h){ return make_float2(__low2float(h), __high2float(h)); }

// ---------- 15-point DFT via Cooley-Tukey 3x5, all-constant twiddles ----------
template<int SIGN>
__device__ __forceinline__ void dft15(const float2* x, float2* X){
    const float S = (float)SIGN;
    const float s3 = 0.8660254037844387f;
    float2 y[5][3];
    #pragma unroll
    for (int n2 = 0; n2 < 5; ++n2){
        float2 a0 = x[n2], a1 = x[5+n2], a2 = x[10+n2];
        float2 t = cadd(a1, a2);
        float2 u = csub(a1, a2);
        float2 m = make_float2(a0.x - 0.5f*t.x, a0.y - 0.5f*t.y);
        float sx = S * s3;
        float2 s = make_float2(-sx*u.y, sx*u.x);
        y[n2][0] = cadd(a0, t);
        y[n2][1] = cadd(m, s);
        y[n2][2] = csub(m, s);
    }
    const float C15[9] = {1.f, 0.9135454576426009f, 0.6691306063588582f, 0.30901699437494745f,
                          -0.10452846326765346f, -0.5f, -0.8090169943749475f,
                          -0.9781476007338057f, -0.9781476007338057f};
    const float S15[9] = {0.f, 0.4067366430758004f, 0.7431448254773942f, 0.9510565162951535f,
                          0.9945218953682733f, 0.8660254037844387f, 0.5877852522924731f,
                          0.20791169081775931f, -0.20791169081775931f};
    #pragma unroll
    for (int n2 = 1; n2 < 5; ++n2){
        #pragma unroll
        for (int k1 = 1; k1 < 3; ++k1){
            const int e = n2*k1;
            y[n2][k1] = cmul(y[n2][k1], make_float2(C15[e], S*S15[e]));
        }
    }
    const float c1 = 0.30901699437494745f, s1 = 0.9510565162951535f;
    const float c2 = -0.8090169943749475f, s2 = 0.5877852522924731f;
    #pragma unroll
    for (int k1 = 0; k1 < 3; ++k1){
        float2 x0 = y[0][k1], x1 = y[1][k1], x2 = y[2][k1], x3 = y[3][k1], x4 = y[4][k1];
        float2 t1 = cadd(x1, x4), t3 = csub(x1, x4);
        float2 t2 = cadd(x2, x3), t4 = csub(x2, x3);
        X[k1] = make_float2(x0.x + t1.x + t2.x, x0.y + t1.y + t2.y);
        float2 u1 = make_float2(x0.x + c1*t1.x + c2*t2.x, x0.y + c1*t1.y + c2*t2.y);
        float2 u2 = make_float2(x0.x + c2*t1.x + c1*t2.x, x0.y + c2*t1.y + c1*t2.y);
        float2 v1 = make_float2(S*(s1*t3.x + s2*t4.x), S*(s1*t3.y + s2*t4.y));
        float2 v2 = make_float2(S*(s2*t3.x - s1*t4.x), S*(s2*t3.y - s1*t4.y));
        X[k1+3]  = make_float2(u1.x - v1.y, u1.y + v1.x);
        X[k1+12] = make_float2(u1.x + v1.y, u1.y - v1.x);
        X[k1+6]  = make_float2(u2.x - v2.y, u2.y + v2.x);
        X[k1+9]  = make_float2(u2.x + v2.y, u2.y - v2.x);
    }
}

// ---------- 16-point DFT via radix-4 x radix-4, all-constant twiddles ----------
template<int SIGN>
__device__ __forceinline__ void dft16(const float2* x, float2* X){
    const float S = (float)SIGN;
    float2 y[4][4];
    #pragma unroll
    for (int n2 = 0; n2 < 4; ++n2){
        float2 a0 = x[n2], a1 = x[4+n2], a2 = x[8+n2], a3 = x[12+n2];
        float2 t0 = cadd(a0,a2), t1 = csub(a0,a2);
        float2 t2 = cadd(a1,a3), t3 = csub(a1,a3);
        float2 it3 = make_float2(-S*t3.y, S*t3.x);
        y[n2][0] = cadd(t0,t2);
        y[n2][2] = csub(t0,t2);
        y[n2][1] = cadd(t1,it3);
        y[n2][3] = csub(t1,it3);
    }
    const float C16[10] = {1.f, 0.9238795325112867f, 0.7071067811865476f, 0.3826834323650898f,
                           0.f, -0.3826834323650898f, -0.7071067811865476f, -0.9238795325112867f,
                           -1.f, -0.9238795325112867f};
    const float S16[10] = {0.f, 0.3826834323650898f, 0.7071067811865476f, 0.9238795325112867f,
                           1.f, 0.9238795325112867f, 0.7071067811865476f, 0.3826834323650898f,
                           0.f, -0.3826834323650898f};
    #pragma unroll
    for (int n2 = 1; n2 < 4; ++n2){
        #pragma unroll
        for (int k1 = 1; k1 < 4; ++k1){
            const int e = n2*k1;
            y[n2][k1] = cmul(y[n2][k1], make_float2(C16[e], S*S16[e]));
        }
    }
    #pragma unroll
    for (int k1 = 0; k1 < 4; ++k1){
        float2 a0 = y[0][k1], a1 = y[1][k1], a2 = y[2][k1], a3 = y[3][k1];
        float2 t0 = cadd(a0,a2), t1 = csub(a0,a2);
        float2 t2 = cadd(a1,a3), t3 = csub(a1,a3);
        float2 it3 = make_float2(-S*t3.y, S*t3.x);
        X[k1]    = cadd(t0,t2);
        X[k1+8]  = csub(t0,t2);
        X[k1+4]  = cadd(t1,it3);
        X[k1+12] = csub(t1,it3);
    }
}

// Wave-autonomous 240-point FFT. LDS row `row` is owned by the 16 lanes
// (row, b=0..15) which all belong to the same wave -> NO __syncthreads needed;
// same-wave LDS ordering (DS pipe in-order + compiler lgkmcnt) suffices.
// v[a] = x[16a+b] preloaded. On return sm[row][k] = X[k].
template<int SIGN>
__device__ __forceinline__ void fft240_wave(float2 (*sm)[PITCH], float2* v, int row, int b){
    const float TWOPI = 6.28318530717958647692f;
    float2 Y[15];
    dft15<SIGN>(v, Y);
    float2 step, tw = make_float2(1.0f, 0.0f);
    {
        float ang = (float)SIGN * TWOPI * (float)b * (1.0f/240.0f);
        __sincosf(ang, &step.y, &step.x);
    }
    #pragma unroll
    for (int d = 0; d < 15; ++d){
        sm[row][b*15 + d] = cmul(Y[d], tw);
        tw = cmul(tw, step);
    }
    __builtin_amdgcn_wave_barrier();   // compiler ordering fence (free)
    if (b < 15){
        float2 Z[16];
        #pragma unroll
        for (int bb = 0; bb < 16; ++bb) Z[bb] = sm[row][bb*15 + b];
        float2 XX[16];
        dft16<SIGN>(Z, XX);
        #pragma unroll
        for (int m = 0; m < 16; ++m) sm[row][15*m + b] = XX[m];
    }
    __builtin_amdgcn_wave_barrier();
}

// Pass A (ZERO barriers): each wave loads its own 4 contiguous rows of x,
// row-FFTs them, stores fp16 blocked [img][kb][h][kwin] (256B/instr).
__global__ __launch_bounds__(256) void passA_rowfft(const float* __restrict__ x,
                                                    __half2* __restrict__ out){
    __shared__ float2 sm[16][PITCH];
    float* smf = (float*)sm;                 // float pitch = 2*PITCH
    int g = blockIdx.x, img = g / NB, h0 = (g % NB) * 16;
    int tid = threadIdx.x, wave = tid >> 6, lane = tid & 63;
    int rl4 = lane >> 4, b = lane & 15, row = wave*4 + rl4;
    const float* src = x + (size_t)img * IMG_PIX + (size_t)(h0 + wave*4) * HW;
    #pragma unroll
    for (int i = 0; i < 15; ++i){
        int f = i*64 + lane;                 // 0..959 over wave's 4 rows
        smf[(wave*4 + f/HW)*(2*PITCH) + (f%HW)] = src[f];
    }
    __builtin_amdgcn_wave_barrier();
    float2 v[15];
    #pragma unroll
    for (int a = 0; a < 15; ++a) v[a] = make_float2(smf[row*(2*PITCH) + 16*a + b], 0.0f);
    __builtin_amdgcn_wave_barrier();
    fft240_wave<-1>(sm, v, row, b);          // sm[row][kw]
    #pragma unroll
    for (int kb = 0; kb < NB; ++kb){
        float2 val = sm[row][kb*16 + b];
        out[((size_t)(img*NB + kb)*HW + h0 + wave*4 + rl4)*16 + b] = f2h(val);
    }
}

// Pass B (4 barriers): stage chunk -> per-wave col FFT -> block-mapped combine
// (keeps y reads at 64B segments) -> per-wave inverse FFT -> flat store.
__global__ __launch_bounds__(256) void passB_col_dc_icol(const __half2* __restrict__ in,
                                                         const float* __restrict__ under,
                                                         const float* __restrict__ Am,
                                                         __half2* __restrict__ out){
    __shared__ float2 sm[16][PITCH];
    int g = blockIdx.x, img = g / NB, s = g % NB, kw0 = s * 16;
    int tid = threadIdx.x, wave = tid >> 6, lane = tid & 63;
    int rl4 = lane >> 4, b = lane & 15, row = wave*4 + rl4;
    const __half2* src = in + (size_t)(img*NB + s) * TILE_ELEMS;   // [h][kwin]
    #pragma unroll
    for (int i = 0; i < 15; ++i){
        int f = i*256 + tid;
        sm[f & 15][f >> 4] = h2f(src[f]);    // transpose to [kwin][h]
    }
    __syncthreads();                          // (1) stage complete
    float2 v[15];
    #pragma unroll
    for (int a = 0; a < 15; ++a) v[a] = sm[row][16*a + b];   // own rows
    __builtin_amdgcn_wave_barrier();
    fft240_wave<-1>(sm, v, row, b);           // sm[row][kh]
    __syncthreads();                          // (2) all FFTs done

    int rl = tid >> 4, bb = tid & 15;         // block-mapped combine
    const float* y0 = under + (size_t)img * (2*IMG_PIX);
    const float* y1 = y0 + IMG_PIX;
    #pragma unroll
    for (int j = 0; j < 15; ++j){
        int kh = j*16 + rl;
        size_t p = (size_t)kh * HW + kw0 + bb;
        float sc = 1.0f - Am[p];
        float2 X = sm[bb][kh];
        sm[bb][kh] = make_float2(sc * X.x + y0[p], sc * X.y + y1[p]);
    }
    __syncthreads();                          // (3) combine complete
    #pragma unroll
    for (int a = 0; a < 15; ++a) v[a] = sm[row][16*a + b];
    __builtin_amdgcn_wave_barrier();
    fft240_wave<+1>(sm, v, row, b);           // sm[row][h]
    __syncthreads();                          // (4) before flat store

    const float inv240 = 1.0f / 240.0f;
    __half2* dst = out + (size_t)(img*NB + s) * TILE_ELEMS;
    #pragma unroll
    for (int i = 0; i < 15; ++i){
        int f = i*256 + tid;
        float2 val = sm[f & 15][f >> 4];
        val.x *= inv240; val.y *= inv240;
        dst[f] = f2h(val);
    }
}

// Pass C (ZERO barriers): per-wave gather of blocked chunks (256B/instr),
// inverse row FFT, abs * 1/240, contiguous store of the wave's 4 output rows.
__global__ __launch_bounds__(256) void passC_irow_abs(const __half2* __restrict__ in,
                                                      float* __restrict__ outp){
    __shared__ float2 sm[16][PITCH];
    int g = blockIdx.x, img = g / NB, h0 = (g % NB) * 16;
    int tid = threadIdx.x, wave = tid >> 6, lane = tid & 63;
    int rl4 = lane >> 4, b = lane & 15, row = wave*4 + rl4;
    #pragma unroll
    for (int kb = 0; kb < NB; ++kb){
        __half2 hv = in[((size_t)(img*NB + kb)*HW + h0 + wave*4 + rl4)*16 + b];
        sm[row][kb*16 + b] = h2f(hv);
    }
    __builtin_amdgcn_wave_barrier();
    float2 v[15];
    #pragma unroll
    for (int a = 0; a < 15; ++a) v[a] = sm[row][16*a + b];
    __builtin_amdgcn_wave_barrier();
    fft240_wave<+1>(sm, v, row, b);           // sm[row][w]
    float* dst = outp + (size_t)img * IMG_PIX + (size_t)(h0 + wave*4) * HW;
    const float inv240 = 1.0f / 240.0f;
    #pragma unroll
    for (int i = 0; i < 15; ++i){
        int f = i*64 + lane;                  // 0..959 over wave's 4 rows
        float2 X = sm[wave*4 + f/HW][f%HW];
        dst[f] = sqrtf(X.x*X.x + X.y*X.y) * inv240;
    }
}

extern "C" void kernel_launch(void* const* d_in, const int* in_sizes, int n_in,
                              void* d_out, int out_size, void* d_ws, size_t ws_size,
                              hipStream_t stream){
    const float* T2   = (const float*)d_in[0];   // [256,1,240,240] f32
    const float* U    = (const float*)d_in[1];   // [256,2,240,240] f32
    const float* Am   = (const float*)d_in[2];   // [240,240] f32
    float* out        = (float*)d_out;           // [256,1,240,240] f32

    const int B = 256;
    __half2* i1 = (__half2*)d_ws;                        // B*57600 half2 = 59 MB
    __half2* i2 = i1 + (size_t)B * IMG_PIX;              // second 59 MB

    dim3 grid(B * NB), block(256);
    passA_rowfft     <<<grid, block, 0, stream>>>(T2, i1);
    passB_col_dc_icol<<<grid, block, 0, stream>>>(i1, U, Am, i2);
    passC_irow_abs   <<<grid, block, 0, stream>>>(i2, out);
}